// Round 1
// 188.346 us; speedup vs baseline: 1.0060x; 1.0060x over previous
//
#include <hip/hip_runtime.h>
#include <math.h>

#define NH      6
#define T_IN    2000
#define T_AUD   960000
#define NB      4
#define C_IN    129
#define C_MID   32
#define CSPLIT  3
#define NC_PER  43          // channels per c-split (43*3 = 129)
#define SPLIT_STRIDE (NB * C_MID * T_IN)   // 256000 floats

// workspace float offsets
#define AMT_OFF   (CSPLIT * SPLIT_STRIDE)          // 768000 floats
#define PF_OFF    (AMT_OFF + NB * NH * T_IN)       // 816000 floats
// total ws: 824000 floats = 3,296,000 B

// ---------------- conv1 partials (no bias), split over channels ----------------
// grid: x = 8 t-tiles, y = b*4 + og (16), z = csplit (3). block 256.
__global__ void k_conv1(const float* __restrict__ f0, const float* __restrict__ mel,
                        const float* __restrict__ w1, float* __restrict__ hpart) {
    const int t0  = blockIdx.x * 256;
    const int b   = blockIdx.y >> 2;
    const int o0  = (blockIdx.y & 3) * 8;
    const int z   = blockIdx.z;
    const int cbase = z * NC_PER;
    const int tid = threadIdx.x;

    __shared__ float xl[NC_PER][264];   // staged cols [t0-4, t0+260)

    for (int idx = tid; idx < NC_PER * 66; idx += 256) {
        const int r = idx / 66;
        const int j = idx - r * 66;
        const int c = cbase + r;
        const float* row = (c == 0) ? (f0 + b * T_IN)
                                    : (mel + ((size_t)(b * 128 + (c - 1))) * T_IN);
        const int gt = t0 - 4 + j * 4;
        float4 v;
        if (gt >= 0 && gt + 3 < T_IN) {
            v = *(const float4*)(row + gt);
        } else {
            v.x = (gt + 0 >= 0 && gt + 0 < T_IN) ? row[gt + 0] : 0.0f;
            v.y = (gt + 1 >= 0 && gt + 1 < T_IN) ? row[gt + 1] : 0.0f;
            v.z = (gt + 2 >= 0 && gt + 2 < T_IN) ? row[gt + 2] : 0.0f;
            v.w = (gt + 3 >= 0 && gt + 3 < T_IN) ? row[gt + 3] : 0.0f;
        }
        *(float4*)(&xl[r][j * 4]) = v;
    }
    __syncthreads();

    float acc[8];
    #pragma unroll
    for (int oo = 0; oo < 8; ++oo) acc[oo] = 0.0f;

    for (int c = 0; c < NC_PER; ++c) {
        const float x0 = xl[c][tid + 2];
        const float x1 = xl[c][tid + 3];
        const float x2 = xl[c][tid + 4];
        const float x3 = xl[c][tid + 5];
        const float x4 = xl[c][tid + 6];
        const int cg = cbase + c;
        #pragma unroll
        for (int oo = 0; oo < 8; ++oo) {
            const float* wp = w1 + (size_t)(o0 + oo) * (C_IN * 5) + cg * 5;  // wave-uniform -> scalar
            acc[oo] = fmaf(wp[0], x0, acc[oo]);
            acc[oo] = fmaf(wp[1], x1, acc[oo]);
            acc[oo] = fmaf(wp[2], x2, acc[oo]);
            acc[oo] = fmaf(wp[3], x3, acc[oo]);
            acc[oo] = fmaf(wp[4], x4, acc[oo]);
        }
    }

    const int t = t0 + tid;
    if (t < T_IN) {
        #pragma unroll
        for (int oo = 0; oo < 8; ++oo)
            hpart[(size_t)z * SPLIT_STRIDE + ((size_t)(b * C_MID + o0 + oo)) * T_IN + t] = acc[oo];
    }
}

// ---------------- per-frame amp table: sum partials + bias + silu + conv2 ------
// grid (8, NB), block 256: thread -> one frame (250 frames/block).
__global__ __launch_bounds__(256) void k_amp(const float* __restrict__ hpart,
        const float* __restrict__ b1, const float* __restrict__ w2,
        const float* __restrict__ b2, float* __restrict__ amT) {
    const int b = blockIdx.y;
    const int i = blockIdx.x * 250 + threadIdx.x;
    if (threadIdx.x >= 250 || i >= T_IN) return;

    float acc[NH];
    #pragma unroll
    for (int h = 0; h < NH; ++h) acc[h] = b2[h];

    #pragma unroll 4
    for (int o = 0; o < C_MID; ++o) {
        const size_t base = ((size_t)(b * C_MID + o)) * T_IN + i;
        const float v = hpart[base] + hpart[SPLIT_STRIDE + base]
                      + hpart[2 * SPLIT_STRIDE + base] + b1[o];
        const float s = v * __builtin_amdgcn_rcpf(1.0f + __expf(-v));
        #pragma unroll
        for (int h = 0; h < NH; ++h)
            acc[h] = fmaf(w2[h * C_MID + o], s, acc[h]);
    }
    #pragma unroll
    for (int h = 0; h < NH; ++h)
        amT[((size_t)(b * NH + h)) * T_IN + i] = acc[h];
}

// ---------------- per-frame phase table: f64 parallel scan -> frac(P_i/48000) --
// grid (NB), block 256: thread -> 8 consecutive frames.
// P_i = 240*f0[0] + 240*sum_{j<i}(f0[j]+f0[j+1])
__global__ __launch_bounds__(256) void k_phase(const float* __restrict__ f0,
                                               float* __restrict__ Pf) {
    const int b   = blockIdx.x;
    const int tid = threadIdx.x;
    const int lane = tid & 63;
    const int wv   = tid >> 6;

    __shared__ float  sf[T_IN];
    __shared__ double wsum[4];

    const float* f0b = f0 + b * T_IN;
    for (int i = tid; i < T_IN; i += 256) sf[i] = f0b[i];
    __syncthreads();

    const int i0 = tid * 8;
    double loc[8];
    double run = 0.0;
    #pragma unroll
    for (int q = 0; q < 8; ++q) {
        loc[q] = run;
        const int i = i0 + q;
        if (i < T_IN - 1) run += (double)sf[i] + (double)sf[i + 1];
    }

    // inclusive wave scan of per-thread totals
    double v = run;
    #pragma unroll
    for (int d = 1; d < 64; d <<= 1) {
        const double o = __shfl_up(v, d, 64);
        if (lane >= d) v += o;
    }
    if (lane == 63) wsum[wv] = v;
    __syncthreads();

    double excl = v - run;                 // exclusive prefix within wave
    for (int w = 0; w < wv; ++w) excl += wsum[w];

    const double base = 240.0 * (double)sf[0];
    #pragma unroll
    for (int q = 0; q < 8; ++q) {
        const int i = i0 + q;
        if (i < T_IN) {
            const double P  = base + 240.0 * (excl + loc[q]);
            const double qq = P * (1.0 / 48000.0);
            Pf[b * T_IN + i] = (float)(qq - floor(qq));
        }
    }
}

// =====================================================================
// k_main2: pure f32 streaming synth. grid (938, NB), block 256,
// 4 consecutive samples/thread (block tile 1024). Frames i_lo..i_lo+4.
// All per-frame quantities come from precomputed tables (amT, Pf).
// aa-mask dropped: f0<500, k<=6 -> sigmoid(>=17.5) == 1.0f in f32.
// =====================================================================
__global__ __launch_bounds__(256) void k_main2(
        const float* __restrict__ f0, const float* __restrict__ noise,
        const float* __restrict__ amT, const float* __restrict__ Pf,
        const float* __restrict__ amp_logscale, const float* __restrict__ phase_offset,
        const float* __restrict__ lnv, const float* __restrict__ lnu,
        float* __restrict__ out) {
    const int b   = blockIdx.y;
    const int tid = threadIdx.x;
    const int s0  = blockIdx.x * 1024;
    const int t0  = s0 + tid * 4;

    __shared__ float sf0[6];        // f0[i_lo .. i_lo+5] (clamped)
    __shared__ float sPf[4];        // frac(P[i]/48000), i_lo..i_lo+3
    __shared__ float sam[NH][5];    // amp rows at i_lo..i_lo+4
    __shared__ float sasc[NH], soff[NH], snv, snu;

    const int ulo = (s0 - 240) < 0 ? 0 : (s0 - 240);
    int i_lo = (unsigned)ulo / 480u;
    if (i_lo > 1998) i_lo = 1998;

    const float* f0b = f0 + b * T_IN;

    if (tid < 6) {
        int idx = i_lo + tid; if (idx > 1999) idx = 1999;
        sf0[tid] = f0b[idx];
    } else if (tid >= 8 && tid < 14) {
        sasc[tid - 8] = 2.0f * __expf(amp_logscale[tid - 8]);   // fold the 2x
    } else if (tid >= 16 && tid < 22) {
        soff[tid - 16] = phase_offset[tid - 16];
    } else if (tid == 22) {
        snv = __expf(lnv[0]);
    } else if (tid == 23) {
        snu = __expf(lnu[0]);
    } else if (tid >= 24 && tid < 28) {
        int idx = i_lo + (tid - 24); if (idx > 1999) idx = 1999;
        sPf[tid - 24] = Pf[b * T_IN + idx];
    } else if (tid >= 32 && tid < 32 + NH * 5) {
        const int r  = tid - 32;
        const int h  = r / 5;
        const int jj = r - h * 5;
        int idx = i_lo + jj; if (idx > 1999) idx = 1999;
        sam[h][jj] = amT[((size_t)(b * NH + h)) * T_IN + idx];
    }
    __syncthreads();

    if (t0 >= T_AUD) return;

    // hoist the noise read so its latency hides under the harmonic math
    const float4 nz = *(const float4*)(noise + (size_t)b * T_AUD + t0);

    const float inv48k = 1.0f / 48000.0f;
    float ph[4], wd[4], voiced[4];
    int li[4];
    #pragma unroll
    for (int j = 0; j < 4; ++j) {
        const int t = t0 + j;
        const int u = (t - 240) < 0 ? 0 : (t - 240);
        int i = (unsigned)u / 480u;
        if (i > 1998) i = 1998;
        li[j] = i - i_lo;
        const int m = t - i * 480 - 240;      // [-240, 719]
        const int n = m + 1;
        const float nf = (float)n;
        const float Wn = (n <= 0) ? 0.0f
                       : ((n <= 480) ? nf * nf * (1.0f / 960.0f) : nf - 240.0f);
        const float fa = sf0[li[j]];
        const float fd = sf0[li[j] + 1] - fa;
        const float pr = sPf[li[j]] + (nf * fa + fd * Wn) * inv48k;
        ph[j] = pr - floorf(pr);

        float w = ((float)m + 0.5f) * (1.0f / 480.0f);
        w = w < 0.0f ? 0.0f : (w > 1.0f ? 1.0f : w);
        wd[j] = w;
        const float f0f = fmaf(fd, w, fa);
        voiced[j] = (f0f > 1.0f) ? 1.0f : 0.0f;
    }

    const size_t outb = (size_t)b * 7 * T_AUD;
    #pragma unroll
    for (int h = 0; h < NH; ++h) {
        const float kf = (float)(h + 1);
        const float s2  = sasc[h];
        const float off = soff[h];
        float r[4];
        #pragma unroll
        for (int j = 0; j < 4; ++j) {
            const float a0  = sam[h][li[j]];
            const float am  = fmaf(sam[h][li[j] + 1] - a0, wd[j], a0);
            const float sig = __builtin_amdgcn_rcpf(1.0f + __expf(-am));
            const float arg = kf * ph[j] + off;            // revolutions
            const float fr  = arg - floorf(arg);
            const float sn  = __builtin_amdgcn_sinf(fr);   // sin(2*pi*fr)
            r[j] = sn * s2 * sig * voiced[j];
        }
        float4 res; res.x = r[0]; res.y = r[1]; res.z = r[2]; res.w = r[3];
        *(float4*)(out + outb + (size_t)h * T_AUD + t0) = res;
    }

    float4 no;
    no.x = nz.x * (voiced[0] > 0.0f ? snv : snu);
    no.y = nz.y * (voiced[1] > 0.0f ? snv : snu);
    no.z = nz.z * (voiced[2] > 0.0f ? snv : snu);
    no.w = nz.w * (voiced[3] > 0.0f ? snv : snu);
    *(float4*)(out + outb + (size_t)6 * T_AUD + t0) = no;
}

extern "C" void kernel_launch(void* const* d_in, const int* in_sizes, int n_in,
                              void* d_out, int out_size, void* d_ws, size_t ws_size,
                              hipStream_t stream) {
    const float* f0   = (const float*)d_in[0];
    const float* mel  = (const float*)d_in[1];
    const float* nois = (const float*)d_in[2];
    const float* w1   = (const float*)d_in[3];
    const float* b1   = (const float*)d_in[4];
    const float* w2   = (const float*)d_in[5];
    const float* b2   = (const float*)d_in[6];
    const float* alog = (const float*)d_in[7];
    const float* poff = (const float*)d_in[8];
    const float* lnv  = (const float*)d_in[9];
    const float* lnu  = (const float*)d_in[10];
    float* out = (float*)d_out;

    // workspace: hpart (768000 f) + amT (48000 f) + Pf (8000 f) = 3,296,000 B
    float* hpart = (float*)d_ws;
    float* amT   = hpart + AMT_OFF;
    float* Pf    = hpart + PF_OFF;

    k_phase<<<dim3(NB), 256, 0, stream>>>(f0, Pf);
    k_conv1<<<dim3(8, 16, CSPLIT), 256, 0, stream>>>(f0, mel, w1, hpart);
    k_amp<<<dim3(8, NB), 256, 0, stream>>>(hpart, b1, w2, b2, amT);
    k_main2<<<dim3((T_AUD + 1023) / 1024, NB), 256, 0, stream>>>(
        f0, nois, amT, Pf, alog, poff, lnv, lnu, out);
}